// Round 2
// baseline (277.616 us; speedup 1.0000x reference)
//
#include <hip/hip_runtime.h>

#define B_     8
#define CIN_   512
#define COUT_  512
#define HW_    64
#define SDIM_  512
#define NPIX   4096      // pixels per image
#define KTOT   4608      // 9*512
#define PADW   66

typedef __attribute__((ext_vector_type(4))) float f32x4;
typedef __attribute__((ext_vector_type(8))) short bf16x8;
typedef __attribute__((ext_vector_type(8))) unsigned short u16x8;

__device__ __forceinline__ float bf2f(unsigned short b) {
    unsigned int u = ((unsigned int)b) << 16;
    return __builtin_bit_cast(float, u);
}
__device__ __forceinline__ unsigned short f2bf(float f) {
    unsigned int u = __builtin_bit_cast(unsigned int, f);
    return (unsigned short)((u + 0x7fffu + ((u >> 16) & 1u)) >> 16);
}
// dtype-flexible scalar load: isbf ? bf16[i] : f32[i]
__device__ __forceinline__ float ldin(const void* p, size_t i, int isbf) {
    return isbf ? bf2f(((const unsigned short*)p)[i]) : ((const float*)p)[i];
}

#define GLD16(g, l) __builtin_amdgcn_global_load_lds( \
    (__attribute__((address_space(1))) void*)(g),     \
    (__attribute__((address_space(3))) void*)(l), 16, 0, 0)

// ---------------- dtype detection: is `style` packed bf16 or f32? ----------------
// low 16 bits of each u32: bf16 value (exp ~[110,140]) vs f32 mantissa bits (uniform)
__global__ void detect_dtype(const unsigned int* __restrict__ style_u32,
                             int* __restrict__ flag) {
    int t = threadIdx.x;                       // 256 threads
    unsigned int w = style_u32[t * 4];         // sample 256 of first 1024 words (safe both dtypes)
    int e = (w >> 7) & 0xFF;
    int isbf = (e >= 110 && e <= 140) ? 1 : 0;
    __shared__ int cnt;
    if (t == 0) cnt = 0;
    __syncthreads();
    atomicAdd(&cnt, isbf);
    __syncthreads();
    if (t == 0) *flag = (cnt >= 128) ? 1 : 0;
}

// ---------------- kernel (k,co) -> Wt (co,k) transpose, + optional f32->bf16 ----------------
__global__ void wt_transpose(const void* __restrict__ kin,
                             unsigned short* __restrict__ wt,
                             const int* __restrict__ flag) {
    __shared__ __align__(16) unsigned short tile[64][72];
    int isbf = *flag;
    int t = threadIdx.x;
    int co0 = blockIdx.x * 64;   // 8 tiles
    int k0  = blockIdx.y * 64;   // 72 tiles
    int r = t >> 2, c16 = (t & 3) << 4;
    if (isbf) {
        const unsigned short* src = (const unsigned short*)kin + (size_t)(k0 + r) * COUT_ + co0 + c16;
        *(u16x8*)&tile[r][c16]     = *(const u16x8*)src;
        *(u16x8*)&tile[r][c16 + 8] = *(const u16x8*)(src + 8);
    } else {
        const float* src = (const float*)kin + (size_t)(k0 + r) * COUT_ + co0 + c16;
#pragma unroll
        for (int q = 0; q < 4; ++q) {
            f32x4 v = *(const f32x4*)(src + q * 4);
#pragma unroll
            for (int j = 0; j < 4; ++j) tile[r][c16 + q * 4 + j] = f2bf(v[j]);
        }
    }
    __syncthreads();
    int c = t >> 2, r16 = (t & 3) << 4;
    u16x8 w0, w1;
#pragma unroll
    for (int j = 0; j < 8; ++j) { w0[j] = tile[r16 + j][c]; w1[j] = tile[r16 + 8 + j][c]; }
    unsigned short* dst = wt + (size_t)(co0 + c) * KTOT + k0 + r16;
    *(u16x8*)dst       = w0;
    *(u16x8*)(dst + 8) = w1;
}

// ---------------- x NCHW -> padded bf16 NHWC (8,66,66,512), interior only ----------------
__global__ void xpose(const void* __restrict__ x,
                      unsigned short* __restrict__ xtp,
                      const int* __restrict__ flag) {
    __shared__ __align__(16) unsigned short tile[64][72];
    int isbf = *flag;
    int t = threadIdx.x;
    int cit = blockIdx.x;   // 8 ci tiles of 64
    int y   = blockIdx.y;   // 64 rows
    int b   = blockIdx.z;   // 8 images
    int ci_l = t >> 2, xo = (t & 3) << 4;
    size_t srcoff = (((size_t)(b * CIN_ + cit * 64 + ci_l)) * HW_ + y) * HW_ + xo;
    if (isbf) {
        const unsigned short* src = (const unsigned short*)x + srcoff;
        *(u16x8*)&tile[ci_l][xo]     = *(const u16x8*)src;
        *(u16x8*)&tile[ci_l][xo + 8] = *(const u16x8*)(src + 8);
    } else {
        const float* src = (const float*)x + srcoff;
#pragma unroll
        for (int q = 0; q < 4; ++q) {
            f32x4 v = *(const f32x4*)(src + q * 4);
#pragma unroll
            for (int j = 0; j < 4; ++j) tile[ci_l][xo + q * 4 + j] = f2bf(v[j]);
        }
    }
    __syncthreads();
    int xl = t >> 2, cio = (t & 3) << 4;
    u16x8 w0, w1;
#pragma unroll
    for (int j = 0; j < 8; ++j) { w0[j] = tile[cio + j][xl]; w1[j] = tile[cio + 8 + j][xl]; }
    unsigned short* dst =
        xtp + (((size_t)b * PADW + (y + 1)) * PADW + (xl + 1)) * CIN_ + cit * 64 + cio;
    *(u16x8*)dst       = w0;
    *(u16x8*)(dst + 8) = w1;
}

// ---------------- m[b,co] = (s+1) * rsqrt((s+1)^2 * sum(kernel^2) + eps) ----------------
__global__ void mod_kernel(const void* __restrict__ style,
                           const void* __restrict__ sscale,
                           const unsigned short* __restrict__ wt,   // canonical bf16 [co][k]
                           float* __restrict__ mmod,
                           const int* __restrict__ flag) {
    int isbf = *flag;
    int co = blockIdx.x, t = threadIdx.x;
    int lane = t & 63, wid = t >> 6;
    float k2 = 0.f;
    const unsigned short* wr = wt + (size_t)co * KTOT;
    for (int k = t; k < KTOT; k += 256) { float v = bf2f(wr[k]); k2 += v * v; }
    float sb[B_];
#pragma unroll
    for (int b = 0; b < B_; ++b) sb[b] = 0.f;
    for (int sd = t; sd < SDIM_; sd += 256) {
        float ss = ldin(sscale, (size_t)sd * COUT_ + co, isbf);
#pragma unroll
        for (int b = 0; b < B_; ++b) sb[b] += ldin(style, b * SDIM_ + sd, isbf) * ss;
    }
    __shared__ float red[4][9];
    float vals[9];
    vals[0] = k2;
#pragma unroll
    for (int b = 0; b < B_; ++b) vals[1 + b] = sb[b];
#pragma unroll
    for (int q = 0; q < 9; ++q) {
        float v = vals[q];
        for (int off = 32; off; off >>= 1) v += __shfl_down(v, off);
        if (lane == 0) red[wid][q] = v;
    }
    __syncthreads();
    if (t < B_) {
        int b = t;
        float k2t = red[0][0] + red[1][0] + red[2][0] + red[3][0];
        float s   = red[0][1 + b] + red[1][1 + b] + red[2][1 + b] + red[3][1 + b];
        float sp1 = s + 1.f;
        mmod[b * COUT_ + co] = sp1 * rsqrtf(sp1 * sp1 * k2t + 1e-8f);
    }
}

// ---------------- implicit-GEMM conv + fused epilogue ----------------
// C[co][pixel] = sum_k Wt[co][k] * A[pixel][k], k = (kh*3+kw)*512 + ci
// tile: 128 co x 128 pixels, BK=64, 4 waves (2x2), 16x16x32 bf16 MFMA
__global__ __launch_bounds__(256) void conv_gemm(
    const unsigned short* __restrict__ wt,
    const unsigned short* __restrict__ xtp,
    const float* __restrict__ mmod,
    const void* __restrict__ noise,
    const void* __restrict__ bias,
    const void* __restrict__ nwp,
    void* __restrict__ out,
    const int* __restrict__ flag) {
    __shared__ __align__(1024) unsigned short Asm[128 * 64];
    __shared__ __align__(1024) unsigned short Bsm[128 * 64];
    int isbf = *flag;
    int tid = threadIdx.x;
    int lane = tid & 63, wid = tid >> 6;
    int gx = blockIdx.x;             // 256 pixel tiles
    int gy = blockIdx.y;             // 4 co tiles
    int b   = gx >> 5;               // image
    int pl0 = (gx & 31) << 7;        // pixel base within image (2 rows)
    int h0  = pl0 >> 6;
    int co0 = gy << 7;
    int wm = wid & 1, wn = wid >> 1;

    const unsigned short* xb = xtp + (size_t)b * (PADW * PADW * CIN_);

    f32x4 acc[4][4];
#pragma unroll
    for (int i = 0; i < 4; ++i)
#pragma unroll
        for (int j = 0; j < 4; ++j) acc[i][j] = (f32x4){0.f, 0.f, 0.f, 0.f};

    int colo = (lane & 7) << 3;   // element offset within BK
    int rsub = lane >> 3;         // 0..7

    for (int ks = 0; ks < 72; ++ks) {
        int khw = ks >> 3;
        int kh = (khw >= 6) ? 2 : ((khw >= 3) ? 1 : 0);
        int kw = khw - kh * 3;
        int ci0 = (ks & 7) << 6;

        // stage A: Wt[co0+row][ks*64 .. +63]  -> Asm[row][64]
        const unsigned short* wtk = wt + (size_t)co0 * KTOT + (ks << 6) + colo;
#pragma unroll
        for (int ii = 0; ii < 4; ++ii) {
            int inst = (ii << 2) + wid;
            int row = (inst << 3) + rsub;
            GLD16(wtk + (size_t)row * KTOT, (char*)Asm + inst * 1024);
        }
        // stage B: x[b][h+kh][w+kw][ci0 .. +63] -> Bsm[p][64]
#pragma unroll
        for (int ii = 0; ii < 4; ++ii) {
            int inst = (ii << 2) + wid;
            int p = (inst << 3) + rsub;
            int h = h0 + (p >> 6);
            int w_ = p & 63;
            const unsigned short* gB =
                xb + ((size_t)((h + kh) * PADW + (w_ + kw)) * CIN_) + ci0 + colo;
            GLD16(gB, (char*)Bsm + inst * 1024);
        }
        __syncthreads();
#pragma unroll
        for (int kk = 0; kk < 2; ++kk) {
            bf16x8 af[4], bfr[4];
#pragma unroll
            for (int mf = 0; mf < 4; ++mf)
                af[mf] = *(const bf16x8*)&Asm[((wm << 6) + (mf << 4) + (lane & 15)) * 64 +
                                              (kk << 5) + ((lane >> 4) << 3)];
#pragma unroll
            for (int nf = 0; nf < 4; ++nf)
                bfr[nf] = *(const bf16x8*)&Bsm[((wn << 6) + (nf << 4) + (lane & 15)) * 64 +
                                               (kk << 5) + ((lane >> 4) << 3)];
#pragma unroll
            for (int mf = 0; mf < 4; ++mf)
#pragma unroll
                for (int nf = 0; nf < 4; ++nf)
                    acc[mf][nf] = __builtin_amdgcn_mfma_f32_16x16x32_bf16(
                        af[mf], bfr[nf], acc[mf][nf], 0, 0, 0);
        }
        __syncthreads();
    }

    // fused epilogue: out = leaky(m*y + nw*noise + bias) * sqrt(2), NCHW
    float nw = ldin(nwp, 0, isbf);
    unsigned short* out16 = (unsigned short*)out;
    float* outf = (float*)out;
#pragma unroll
    for (int mf = 0; mf < 4; ++mf) {
        int cobase = co0 + (wm << 6) + (mf << 4) + ((lane >> 4) << 2);
        f32x4 mv = *(const f32x4*)&mmod[b * COUT_ + cobase];
        float bb[4];
#pragma unroll
        for (int r = 0; r < 4; ++r) bb[r] = ldin(bias, cobase + r, isbf);
#pragma unroll
        for (int nf = 0; nf < 4; ++nf) {
            int pix = pl0 + (wn << 6) + (nf << 4) + (lane & 15);
            float nv = nw * ldin(noise, b * NPIX + pix, isbf);
#pragma unroll
            for (int r = 0; r < 4; ++r) {
                float v = acc[mf][nf][r] * mv[r] + nv + bb[r];
                v = (v < 0.f ? v * 0.2f : v) * 1.41421356237f;
                size_t oidx = ((size_t)(b * COUT_ + cobase + r)) * NPIX + pix;
                if (isbf) out16[oidx] = f2bf(v);
                else      outf[oidx]  = v;
            }
        }
    }
}

extern "C" void kernel_launch(void* const* d_in, const int* in_sizes, int n_in,
                              void* d_out, int out_size, void* d_ws, size_t ws_size,
                              hipStream_t stream) {
    const void* x      = d_in[0];
    const void* style  = d_in[1];
    const void* noise  = d_in[2];
    const void* kin    = d_in[3];
    const void* sscale = d_in[4];
    const void* bias   = d_in[5];
    const void* nwp    = d_in[6];

    char* ws = (char*)d_ws;
    int* flag = (int*)ws;                                           // 4 B (+ pad to 256)
    const size_t xtp_off  = 256;
    const size_t xtp_bytes = (size_t)B_ * PADW * PADW * CIN_ * 2;   // 35,684,352
    const size_t wt_bytes  = (size_t)COUT_ * KTOT * 2;              //  4,718,592
    unsigned short* xtp = (unsigned short*)(ws + xtp_off);
    unsigned short* wtr = (unsigned short*)(ws + xtp_off + xtp_bytes);
    float* mmod         = (float*)(ws + xtp_off + xtp_bytes + wt_bytes);  // 16,384 B

    detect_dtype<<<1, 256, 0, stream>>>((const unsigned int*)style, flag);
    hipMemsetAsync(xtp, 0, xtp_bytes, stream);                      // zero halo pad
    wt_transpose<<<dim3(8, 72), 256, 0, stream>>>(kin, wtr, flag);
    xpose<<<dim3(8, 64, 8), 256, 0, stream>>>(x, xtp, flag);
    mod_kernel<<<512, 256, 0, stream>>>(style, sscale, wtr, mmod, flag);
    conv_gemm<<<dim3(256, 4), 256, 0, stream>>>(wtr, xtp, mmod, noise, bias, nwp, d_out, flag);
}

// Round 3
// 213.053 us; speedup vs baseline: 1.3030x; 1.3030x over previous
//
#include <hip/hip_runtime.h>

#define B_     8
#define CIN_   512
#define COUT_  512
#define HW_    64
#define SDIM_  512
#define NPIX   4096      // pixels per image
#define KTOT   4608      // 9*512
#define PADW   66

typedef __attribute__((ext_vector_type(4))) float f32x4;
typedef __attribute__((ext_vector_type(8))) short bf16x8;
typedef __attribute__((ext_vector_type(8))) unsigned short u16x8;

__device__ __forceinline__ float bf2f(unsigned short b) {
    unsigned int u = ((unsigned int)b) << 16;
    return __builtin_bit_cast(float, u);
}
__device__ __forceinline__ unsigned short f2bf(float f) {
    unsigned int u = __builtin_bit_cast(unsigned int, f);
    return (unsigned short)((u + 0x7fffu + ((u >> 16) & 1u)) >> 16);
}
__device__ __forceinline__ float ldin(const void* p, size_t i, int isbf) {
    return isbf ? bf2f(((const unsigned short*)p)[i]) : ((const float*)p)[i];
}

#define GLD16(g, l) __builtin_amdgcn_global_load_lds( \
    (__attribute__((address_space(1))) void*)(g),     \
    (__attribute__((address_space(3))) void*)(l), 16, 0, 0)

// ---------------- dtype detection (unchanged, verified) ----------------
__global__ void detect_dtype(const unsigned int* __restrict__ style_u32,
                             int* __restrict__ flag) {
    int t = threadIdx.x;
    unsigned int w = style_u32[t * 4];
    int e = (w >> 7) & 0xFF;
    int isbf = (e >= 110 && e <= 140) ? 1 : 0;
    __shared__ int cnt;
    if (t == 0) cnt = 0;
    __syncthreads();
    atomicAdd(&cnt, isbf);
    __syncthreads();
    if (t == 0) *flag = (cnt >= 128) ? 1 : 0;
}

// ---------------- kernel (k,co) -> Wt (co,k) transpose (unchanged) ----------------
__global__ void wt_transpose(const void* __restrict__ kin,
                             unsigned short* __restrict__ wt,
                             const int* __restrict__ flag) {
    __shared__ __align__(16) unsigned short tile[64][72];
    int isbf = *flag;
    int t = threadIdx.x;
    int co0 = blockIdx.x * 64;
    int k0  = blockIdx.y * 64;
    int r = t >> 2, c16 = (t & 3) << 4;
    if (isbf) {
        const unsigned short* src = (const unsigned short*)kin + (size_t)(k0 + r) * COUT_ + co0 + c16;
        *(u16x8*)&tile[r][c16]     = *(const u16x8*)src;
        *(u16x8*)&tile[r][c16 + 8] = *(const u16x8*)(src + 8);
    } else {
        const float* src = (const float*)kin + (size_t)(k0 + r) * COUT_ + co0 + c16;
#pragma unroll
        for (int q = 0; q < 4; ++q) {
            f32x4 v = *(const f32x4*)(src + q * 4);
#pragma unroll
            for (int j = 0; j < 4; ++j) tile[r][c16 + q * 4 + j] = f2bf(v[j]);
        }
    }
    __syncthreads();
    int c = t >> 2, r16 = (t & 3) << 4;
    u16x8 w0, w1;
#pragma unroll
    for (int j = 0; j < 8; ++j) { w0[j] = tile[r16 + j][c]; w1[j] = tile[r16 + 8 + j][c]; }
    unsigned short* dst = wt + (size_t)(co0 + c) * KTOT + k0 + r16;
    *(u16x8*)dst       = w0;
    *(u16x8*)(dst + 8) = w1;
}

// ---------------- x NCHW -> padded bf16 NHWC (unchanged) ----------------
__global__ void xpose(const void* __restrict__ x,
                      unsigned short* __restrict__ xtp,
                      const int* __restrict__ flag) {
    __shared__ __align__(16) unsigned short tile[64][72];
    int isbf = *flag;
    int t = threadIdx.x;
    int cit = blockIdx.x;
    int y   = blockIdx.y;
    int b   = blockIdx.z;
    int ci_l = t >> 2, xo = (t & 3) << 4;
    size_t srcoff = (((size_t)(b * CIN_ + cit * 64 + ci_l)) * HW_ + y) * HW_ + xo;
    if (isbf) {
        const unsigned short* src = (const unsigned short*)x + srcoff;
        *(u16x8*)&tile[ci_l][xo]     = *(const u16x8*)src;
        *(u16x8*)&tile[ci_l][xo + 8] = *(const u16x8*)(src + 8);
    } else {
        const float* src = (const float*)x + srcoff;
#pragma unroll
        for (int q = 0; q < 4; ++q) {
            f32x4 v = *(const f32x4*)(src + q * 4);
#pragma unroll
            for (int j = 0; j < 4; ++j) tile[ci_l][xo + q * 4 + j] = f2bf(v[j]);
        }
    }
    __syncthreads();
    int xl = t >> 2, cio = (t & 3) << 4;
    u16x8 w0, w1;
#pragma unroll
    for (int j = 0; j < 8; ++j) { w0[j] = tile[cio + j][xl]; w1[j] = tile[cio + 8 + j][xl]; }
    unsigned short* dst =
        xtp + (((size_t)b * PADW + (y + 1)) * PADW + (xl + 1)) * CIN_ + cit * 64 + cio;
    *(u16x8*)dst       = w0;
    *(u16x8*)(dst + 8) = w1;
}

// ---------------- mod scale (unchanged) ----------------
__global__ void mod_kernel(const void* __restrict__ style,
                           const void* __restrict__ sscale,
                           const unsigned short* __restrict__ wt,
                           float* __restrict__ mmod,
                           const int* __restrict__ flag) {
    int isbf = *flag;
    int co = blockIdx.x, t = threadIdx.x;
    int lane = t & 63, wid = t >> 6;
    float k2 = 0.f;
    const unsigned short* wr = wt + (size_t)co * KTOT;
    for (int k = t; k < KTOT; k += 256) { float v = bf2f(wr[k]); k2 += v * v; }
    float sb[B_];
#pragma unroll
    for (int b = 0; b < B_; ++b) sb[b] = 0.f;
    for (int sd = t; sd < SDIM_; sd += 256) {
        float ss = ldin(sscale, (size_t)sd * COUT_ + co, isbf);
#pragma unroll
        for (int b = 0; b < B_; ++b) sb[b] += ldin(style, b * SDIM_ + sd, isbf) * ss;
    }
    __shared__ float red[4][9];
    float vals[9];
    vals[0] = k2;
#pragma unroll
    for (int b = 0; b < B_; ++b) vals[1 + b] = sb[b];
#pragma unroll
    for (int q = 0; q < 9; ++q) {
        float v = vals[q];
        for (int off = 32; off; off >>= 1) v += __shfl_down(v, off);
        if (lane == 0) red[wid][q] = v;
    }
    __syncthreads();
    if (t < B_) {
        int b = t;
        float k2t = red[0][0] + red[1][0] + red[2][0] + red[3][0];
        float s   = red[0][1 + b] + red[1][1 + b] + red[2][1 + b] + red[3][1 + b];
        float sp1 = s + 1.f;
        mmod[b * COUT_ + co] = sp1 * rsqrtf(sp1 * sp1 * k2t + 1e-8f);
    }
}

// ---------------- implicit-GEMM conv, 256x256 tile, 8 waves, dbuf + counted vmcnt ----------------
// C[co][pixel]; A = Wt[256 co][BK=64], B = x[256 pix][64].
// LDS swizzle (T2, both-sides): linear gld16 dest + pre-swizzled global source column
//   ce_src = ((lane&7) ^ (lane>>3)) << 3 ; reads XOR elem-bits 3..5 with (row&7)<<3.
__global__ __launch_bounds__(512, 2) void conv_gemm(
    const unsigned short* __restrict__ wt,
    const unsigned short* __restrict__ xtp,
    const float* __restrict__ mmod,
    const void* __restrict__ noise,
    const void* __restrict__ bias,
    const void* __restrict__ nwp,
    void* __restrict__ out,
    const int* __restrict__ flag) {
    __shared__ __align__(1024) unsigned short Asm[2][256 * 64];   // 64 KiB
    __shared__ __align__(1024) unsigned short Bsm[2][256 * 64];   // 64 KiB
    int isbf = *flag;
    int tid = threadIdx.x;
    int lane = tid & 63, wid = tid >> 6;
    int lr = lane & 15, hi = lane >> 4;
    int wm = wid >> 2, wn = wid & 3;          // 2 x 4 wave grid

    // XCD-chunked bijective swizzle (256 blocks, 8 XCDs)
    int bid = blockIdx.x;
    int swz = (bid & 7) * 32 + (bid >> 3);
    int gy = swz >> 7;                        // co tile (0..1)
    int nb = swz & 127;
    int b  = nb >> 4;                         // image
    int nt = nb & 15;                         // pixel tile in image
    int pl0 = nt << 8;                        // 256 pixels = 4 rows
    int h0  = pl0 >> 6;
    int co0 = gy << 8;

    const unsigned short* xb = xtp + (size_t)b * (PADW * PADW * CIN_);

    f32x4 acc[8][4];
#pragma unroll
    for (int i = 0; i < 8; ++i)
#pragma unroll
        for (int j = 0; j < 4; ++j) acc[i][j] = (f32x4){0.f, 0.f, 0.f, 0.f};

    int rsub = lane >> 3;
    int ce_src = ((lane & 7) ^ rsub) << 3;    // pre-swizzled source column (elements)

    // ---- stage one K-tile (A + B) into buffer pp; 8 gld16 per wave ----
    auto stage = [&](int tt, int pp) {
        int khw = tt >> 3;
        int kh = khw / 3, kw = khw - kh * 3;
        int ci0 = (tt & 7) << 6;
        const unsigned short* srcA =
            wt + (size_t)(co0 + (wid << 5) + rsub) * KTOT + (tt << 6) + ce_src;
        char* ldA = (char*)&Asm[pp][0] + (wid << 12);
#pragma unroll
        for (int i = 0; i < 4; ++i)
            GLD16(srcA + (size_t)(i << 3) * KTOT, ldA + (i << 10));
        char* ldB = (char*)&Bsm[pp][0] + (wid << 12);
#pragma unroll
        for (int i = 0; i < 4; ++i) {
            int p = (wid << 5) + (i << 3) + rsub;
            int h = h0 + (p >> 6), wc = p & 63;
            const unsigned short* srcB =
                xb + ((size_t)(h + kh) * PADW + (wc + kw)) * CIN_ + ci0 + ce_src;
            GLD16(srcB, ldB + (i << 10));
        }
    };

    // prologue: tiles 0,1 in flight; wait for tile 0 (8 newest stay outstanding)
    stage(0, 0);
    stage(1, 1);
    asm volatile("s_waitcnt vmcnt(8)" ::: "memory");
    __builtin_amdgcn_s_barrier();
    __builtin_amdgcn_sched_barrier(0);

    int swzr = (lane & 7) << 3;               // read-side XOR term: (row&7)<<3 == (lane&7)<<3
    for (int t = 0; t < 72; ++t) {
        int p = t & 1;
        const unsigned short* As = &Asm[p][0];
        const unsigned short* Bs = &Bsm[p][0];
#pragma unroll
        for (int kk = 0; kk < 2; ++kk) {
            bf16x8 af[8], bf[4];
            int ceb = (kk << 5);
#pragma unroll
            for (int mf = 0; mf < 8; ++mf) {
                int row = (wm << 7) + (mf << 4) + lr;
                af[mf] = *(const bf16x8*)&As[row * 64 + ((ceb + (hi << 3)) ^ swzr)];
            }
#pragma unroll
            for (int nf = 0; nf < 4; ++nf) {
                int row = (wn << 6) + (nf << 4) + lr;
                bf[nf] = *(const bf16x8*)&Bs[row * 64 + ((ceb + (hi << 3)) ^ swzr)];
            }
            __builtin_amdgcn_s_setprio(1);
#pragma unroll
            for (int mf = 0; mf < 8; ++mf)
#pragma unroll
                for (int nf = 0; nf < 4; ++nf)
                    acc[mf][nf] = __builtin_amdgcn_mfma_f32_16x16x32_bf16(
                        af[mf], bf[nf], acc[mf][nf], 0, 0, 0);
            __builtin_amdgcn_s_setprio(0);
        }
        // all reads of buf[p] complete before anyone overwrites it
        asm volatile("s_waitcnt lgkmcnt(0)" ::: "memory");
        __builtin_amdgcn_sched_barrier(0);
        __builtin_amdgcn_s_barrier();
        if (t < 70) {
            stage(t + 2, p);
            asm volatile("s_waitcnt vmcnt(8)" ::: "memory");  // tile t+1 landed; t+2 in flight
        } else {
            asm volatile("s_waitcnt vmcnt(0)" ::: "memory");  // tail drain
        }
        __builtin_amdgcn_s_barrier();
        __builtin_amdgcn_sched_barrier(0);
    }

    // fused epilogue: out = leaky(m*y + nw*noise + bias) * sqrt(2), NCHW
    float nw = ldin(nwp, 0, isbf);
    unsigned short* out16 = (unsigned short*)out;
    float* outf = (float*)out;
#pragma unroll
    for (int mf = 0; mf < 8; ++mf) {
        int cobase = co0 + (wm << 7) + (mf << 4) + (hi << 2);
        f32x4 mv = *(const f32x4*)&mmod[b * COUT_ + cobase];
        float bb[4];
#pragma unroll
        for (int r = 0; r < 4; ++r) bb[r] = ldin(bias, cobase + r, isbf);
#pragma unroll
        for (int nf = 0; nf < 4; ++nf) {
            int pix = pl0 + (wn << 6) + (nf << 4) + lr;
            float nv = nw * ldin(noise, b * NPIX + pix, isbf);
#pragma unroll
            for (int r = 0; r < 4; ++r) {
                float v = acc[mf][nf][r] * mv[r] + nv + bb[r];
                v = (v < 0.f ? v * 0.2f : v) * 1.41421356237f;
                size_t oidx = ((size_t)(b * COUT_ + cobase + r)) * NPIX + pix;
                if (isbf) out16[oidx] = f2bf(v);
                else      outf[oidx]  = v;
            }
        }
    }
}

extern "C" void kernel_launch(void* const* d_in, const int* in_sizes, int n_in,
                              void* d_out, int out_size, void* d_ws, size_t ws_size,
                              hipStream_t stream) {
    const void* x      = d_in[0];
    const void* style  = d_in[1];
    const void* noise  = d_in[2];
    const void* kin    = d_in[3];
    const void* sscale = d_in[4];
    const void* bias   = d_in[5];
    const void* nwp    = d_in[6];

    char* ws = (char*)d_ws;
    int* flag = (int*)ws;
    const size_t xtp_off  = 256;
    const size_t xtp_bytes = (size_t)B_ * PADW * PADW * CIN_ * 2;
    const size_t wt_bytes  = (size_t)COUT_ * KTOT * 2;
    unsigned short* xtp = (unsigned short*)(ws + xtp_off);
    unsigned short* wtr = (unsigned short*)(ws + xtp_off + xtp_bytes);
    float* mmod         = (float*)(ws + xtp_off + xtp_bytes + wt_bytes);

    detect_dtype<<<1, 256, 0, stream>>>((const unsigned int*)style, flag);
    hipMemsetAsync(xtp, 0, xtp_bytes, stream);
    wt_transpose<<<dim3(8, 72), 256, 0, stream>>>(kin, wtr, flag);
    xpose<<<dim3(8, 64, 8), 256, 0, stream>>>(x, xtp, flag);
    mod_kernel<<<512, 256, 0, stream>>>(style, sscale, wtr, mmod, flag);
    conv_gemm<<<256, 512, 0, stream>>>(wtr, xtp, mmod, noise, bias, nwp, d_out, flag);
}

// Round 4
// 194.435 us; speedup vs baseline: 1.4278x; 1.0958x over previous
//
#include <hip/hip_runtime.h>

#define B_     8
#define CIN_   512
#define COUT_  512
#define HW_    64
#define SDIM_  512
#define NPIX   4096      // pixels per image
#define KTOT   4608      // 9*512
#define PADW   66

typedef __attribute__((ext_vector_type(4))) float f32x4;
typedef __attribute__((ext_vector_type(8))) short bf16x8;
typedef __attribute__((ext_vector_type(8))) unsigned short u16x8;

__device__ __forceinline__ float bf2f(unsigned short b) {
    unsigned int u = ((unsigned int)b) << 16;
    return __builtin_bit_cast(float, u);
}
__device__ __forceinline__ unsigned short f2bf(float f) {
    unsigned int u = __builtin_bit_cast(unsigned int, f);
    return (unsigned short)((u + 0x7fffu + ((u >> 16) & 1u)) >> 16);
}
__device__ __forceinline__ float ldin(const void* p, size_t i, int isbf) {
    return isbf ? bf2f(((const unsigned short*)p)[i]) : ((const float*)p)[i];
}

#define GLD16(g, l) __builtin_amdgcn_global_load_lds( \
    (__attribute__((address_space(1))) void*)(g),     \
    (__attribute__((address_space(3))) void*)(l), 16, 0, 0)

// ---------------- dtype detection (unchanged, verified) ----------------
__global__ void detect_dtype(const unsigned int* __restrict__ style_u32,
                             int* __restrict__ flag) {
    int t = threadIdx.x;
    unsigned int w = style_u32[t * 4];
    int e = (w >> 7) & 0xFF;
    int isbf = (e >= 110 && e <= 140) ? 1 : 0;
    __shared__ int cnt;
    if (t == 0) cnt = 0;
    __syncthreads();
    atomicAdd(&cnt, isbf);
    __syncthreads();
    if (t == 0) *flag = (cnt >= 128) ? 1 : 0;
}

// ---------------- zero only the halo ring of xtp (replaces 35.7MB memset) ----------------
__global__ void halo_zero(unsigned short* __restrict__ xtp) {
    int idx = blockIdx.x;        // 0..259
    int b = blockIdx.y;
    int y, x;
    if (idx < 66)       { y = 0;  x = idx; }
    else if (idx < 132) { y = 65; x = idx - 66; }
    else if (idx < 196) { x = 0;  y = idx - 131; }
    else                { x = 65; y = idx - 195; }
    unsigned int* dst = (unsigned int*)(xtp + (((size_t)b * PADW + y) * PADW + x) * CIN_);
    dst[threadIdx.x] = 0;        // 256 threads x 4B = 512 bf16
}

// ---------------- kernel (k,co) -> Wt (co,k) transpose (unchanged) ----------------
__global__ void wt_transpose(const void* __restrict__ kin,
                             unsigned short* __restrict__ wt,
                             const int* __restrict__ flag) {
    __shared__ __align__(16) unsigned short tile[64][72];
    int isbf = *flag;
    int t = threadIdx.x;
    int co0 = blockIdx.x * 64;
    int k0  = blockIdx.y * 64;
    int r = t >> 2, c16 = (t & 3) << 4;
    if (isbf) {
        const unsigned short* src = (const unsigned short*)kin + (size_t)(k0 + r) * COUT_ + co0 + c16;
        *(u16x8*)&tile[r][c16]     = *(const u16x8*)src;
        *(u16x8*)&tile[r][c16 + 8] = *(const u16x8*)(src + 8);
    } else {
        const float* src = (const float*)kin + (size_t)(k0 + r) * COUT_ + co0 + c16;
#pragma unroll
        for (int q = 0; q < 4; ++q) {
            f32x4 v = *(const f32x4*)(src + q * 4);
#pragma unroll
            for (int j = 0; j < 4; ++j) tile[r][c16 + q * 4 + j] = f2bf(v[j]);
        }
    }
    __syncthreads();
    int c = t >> 2, r16 = (t & 3) << 4;
    u16x8 w0, w1;
#pragma unroll
    for (int j = 0; j < 8; ++j) { w0[j] = tile[r16 + j][c]; w1[j] = tile[r16 + 8 + j][c]; }
    unsigned short* dst = wt + (size_t)(co0 + c) * KTOT + k0 + r16;
    *(u16x8*)dst       = w0;
    *(u16x8*)(dst + 8) = w1;
}

// ---------------- x NCHW -> padded bf16 NHWC (unchanged) ----------------
__global__ void xpose(const void* __restrict__ x,
                      unsigned short* __restrict__ xtp,
                      const int* __restrict__ flag) {
    __shared__ __align__(16) unsigned short tile[64][72];
    int isbf = *flag;
    int t = threadIdx.x;
    int cit = blockIdx.x;
    int y   = blockIdx.y;
    int b   = blockIdx.z;
    int ci_l = t >> 2, xo = (t & 3) << 4;
    size_t srcoff = (((size_t)(b * CIN_ + cit * 64 + ci_l)) * HW_ + y) * HW_ + xo;
    if (isbf) {
        const unsigned short* src = (const unsigned short*)x + srcoff;
        *(u16x8*)&tile[ci_l][xo]     = *(const u16x8*)src;
        *(u16x8*)&tile[ci_l][xo + 8] = *(const u16x8*)(src + 8);
    } else {
        const float* src = (const float*)x + srcoff;
#pragma unroll
        for (int q = 0; q < 4; ++q) {
            f32x4 v = *(const f32x4*)(src + q * 4);
#pragma unroll
            for (int j = 0; j < 4; ++j) tile[ci_l][xo + q * 4 + j] = f2bf(v[j]);
        }
    }
    __syncthreads();
    int xl = t >> 2, cio = (t & 3) << 4;
    u16x8 w0, w1;
#pragma unroll
    for (int j = 0; j < 8; ++j) { w0[j] = tile[cio + j][xl]; w1[j] = tile[cio + 8 + j][xl]; }
    unsigned short* dst =
        xtp + (((size_t)b * PADW + (y + 1)) * PADW + (xl + 1)) * CIN_ + cit * 64 + cio;
    *(u16x8*)dst       = w0;
    *(u16x8*)(dst + 8) = w1;
}

// ---------------- mod scale (unchanged) ----------------
__global__ void mod_kernel(const void* __restrict__ style,
                           const void* __restrict__ sscale,
                           const unsigned short* __restrict__ wt,
                           float* __restrict__ mmod,
                           const int* __restrict__ flag) {
    int isbf = *flag;
    int co = blockIdx.x, t = threadIdx.x;
    int lane = t & 63, wid = t >> 6;
    float k2 = 0.f;
    const unsigned short* wr = wt + (size_t)co * KTOT;
    for (int k = t; k < KTOT; k += 256) { float v = bf2f(wr[k]); k2 += v * v; }
    float sb[B_];
#pragma unroll
    for (int b = 0; b < B_; ++b) sb[b] = 0.f;
    for (int sd = t; sd < SDIM_; sd += 256) {
        float ss = ldin(sscale, (size_t)sd * COUT_ + co, isbf);
#pragma unroll
        for (int b = 0; b < B_; ++b) sb[b] += ldin(style, b * SDIM_ + sd, isbf) * ss;
    }
    __shared__ float red[4][9];
    float vals[9];
    vals[0] = k2;
#pragma unroll
    for (int b = 0; b < B_; ++b) vals[1 + b] = sb[b];
#pragma unroll
    for (int q = 0; q < 9; ++q) {
        float v = vals[q];
        for (int off = 32; off; off >>= 1) v += __shfl_down(v, off);
        if (lane == 0) red[wid][q] = v;
    }
    __syncthreads();
    if (t < B_) {
        int b = t;
        float k2t = red[0][0] + red[1][0] + red[2][0] + red[3][0];
        float s   = red[0][1 + b] + red[1][1 + b] + red[2][1 + b] + red[3][1 + b];
        float sp1 = s + 1.f;
        mmod[b * COUT_ + co] = sp1 * rsqrtf(sp1 * sp1 * k2t + 1e-8f);
    }
}

// ---------------- implicit-GEMM conv, 256x256, 8 waves, 4-phase/K-tile pipeline ----------------
// Per K-tile t (buf t&1), phases P0..P3, each: {ds_read frags | stage 2 pieces} ->
// barrier -> lgkmcnt(0) -> setprio(1) -> 16 MFMA -> setprio(0) -> barrier.
// Staging bands (64 rows each) restaged only after their last read phase:
//   A0,A2,B*: last read P2 ; A1,A3: last read P3.
//   t.P0: B0,B1(t+1)  t.P1: B2,B3(t+1)  t.P2: A1,A3(t+1)  t.P3: A0,A2(t+2) + vmcnt(2)
__global__ __launch_bounds__(512, 2) void conv_gemm(
    const unsigned short* __restrict__ wt,
    const unsigned short* __restrict__ xtp,
    const float* __restrict__ mmod,
    const void* __restrict__ noise,
    const void* __restrict__ bias,
    const void* __restrict__ nwp,
    void* __restrict__ out,
    const int* __restrict__ flag) {
    __shared__ __align__(1024) unsigned short Asm[2][256 * 64];   // 64 KiB
    __shared__ __align__(1024) unsigned short Bsm[2][256 * 64];   // 64 KiB
    int isbf = *flag;
    int tid = threadIdx.x;
    int lane = tid & 63, wid = tid >> 6;
    int lr = lane & 15, hi = lane >> 4;
    int wm = wid >> 2, wn = wid & 3;          // 2 x 4 wave grid

    int bid = blockIdx.x;
    int swz = (bid & 7) * 32 + (bid >> 3);    // XCD-chunked bijective (256 % 8 == 0)
    int gy = swz >> 7;
    int nb = swz & 127;
    int b  = nb >> 4;
    int nt = nb & 15;
    int pl0 = nt << 8;                        // 256 pixels = 4 rows
    int h0  = pl0 >> 6;
    int co0 = gy << 8;

    const unsigned short* xb = xtp + (size_t)b * (PADW * PADW * CIN_);

    f32x4 acc[8][4];
#pragma unroll
    for (int i = 0; i < 8; ++i)
#pragma unroll
        for (int j = 0; j < 4; ++j) acc[i][j] = (f32x4){0.f, 0.f, 0.f, 0.f};

    int rsub = lane >> 3;
    int ce_src = ((lane & 7) ^ rsub) << 3;    // pre-swizzled source column (elements)
    int swzr = (lane & 7) << 3;               // read-side XOR

    // stage band q (64 rows) of A/B for tile tt into buffer pp; 1 gld16 per wave
    auto stageA = [&](int tt, int pp, int q) {
        const unsigned short* srcA =
            wt + (size_t)(co0 + (q << 6) + (wid << 3) + rsub) * KTOT + (tt << 6) + ce_src;
        GLD16(srcA, (char*)&Asm[pp][0] + (q << 13) + (wid << 10));
    };
    auto stageB = [&](int tt, int pp, int q) {
        int khw = tt >> 3;
        int kh = (khw >= 6) ? 2 : ((khw >= 3) ? 1 : 0);
        int kw = khw - kh * 3;
        int ci0 = (tt & 7) << 6;
        int wc = ((wid << 3) + rsub) & 63;    // pixel within row; row = h0 + q
        const unsigned short* srcB =
            xb + ((size_t)(h0 + q + kh) * PADW + (wc + kw)) * CIN_ + ci0 + ce_src;
        GLD16(srcB, (char*)&Bsm[pp][0] + (q << 13) + (wid << 10));
    };

    // prologue: tiles 0 and 1 fully staged
#pragma unroll
    for (int q = 0; q < 4; ++q) { stageA(0, 0, q); stageB(0, 0, q); }
#pragma unroll
    for (int q = 0; q < 4; ++q) { stageA(1, 1, q); stageB(1, 1, q); }
    asm volatile("s_waitcnt vmcnt(8)" ::: "memory");   // tile 0 landed
    __builtin_amdgcn_s_barrier();
    __builtin_amdgcn_sched_barrier(0);

    for (int t = 0; t < 72; ++t) {
        int p = t & 1, pn = p ^ 1;
        const unsigned short* As = &Asm[p][0];
        const unsigned short* Bs = &Bsm[p][0];
        bool sN = (t >= 1 && t <= 70);        // stage tile t+1 (t=0: prestaged)
        bool s2 = (t <= 69);                  // stage tile t+2 A0,A2

        // ---------- P0: read af[0-3]k0 + bf[0-3]k0 ; stage B0,B1(t+1) ; MFMA mf0-3 k0 ----------
        bf16x8 a0[4], bk0[4];
#pragma unroll
        for (int i = 0; i < 4; ++i)
            a0[i] = *(const bf16x8*)&As[(((wm << 7) + (i << 4) + lr) << 6) + ((hi << 3) ^ swzr)];
#pragma unroll
        for (int i = 0; i < 4; ++i)
            bk0[i] = *(const bf16x8*)&Bs[(((wn << 6) + (i << 4) + lr) << 6) + ((hi << 3) ^ swzr)];
        if (sN) { stageB(t + 1, pn, 0); stageB(t + 1, pn, 1); }
        __builtin_amdgcn_sched_barrier(0);
        __builtin_amdgcn_s_barrier();
        asm volatile("s_waitcnt lgkmcnt(0)" ::: "memory");
        __builtin_amdgcn_sched_barrier(0);
        __builtin_amdgcn_s_setprio(1);
#pragma unroll
        for (int mf = 0; mf < 4; ++mf)
#pragma unroll
            for (int nf = 0; nf < 4; ++nf)
                acc[mf][nf] = __builtin_amdgcn_mfma_f32_16x16x32_bf16(a0[mf], bk0[nf], acc[mf][nf], 0, 0, 0);
        __builtin_amdgcn_s_setprio(0);
        __builtin_amdgcn_s_barrier();

        // ---------- P1: read af[4-7]k0 ; stage B2,B3(t+1) ; MFMA mf4-7 k0 ----------
        bf16x8 a1[4];
#pragma unroll
        for (int i = 0; i < 4; ++i)
            a1[i] = *(const bf16x8*)&As[(((wm << 7) + ((i + 4) << 4) + lr) << 6) + ((hi << 3) ^ swzr)];
        if (sN) { stageB(t + 1, pn, 2); stageB(t + 1, pn, 3); }
        __builtin_amdgcn_sched_barrier(0);
        __builtin_amdgcn_s_barrier();
        asm volatile("s_waitcnt lgkmcnt(0)" ::: "memory");
        __builtin_amdgcn_sched_barrier(0);
        __builtin_amdgcn_s_setprio(1);
#pragma unroll
        for (int mf = 0; mf < 4; ++mf)
#pragma unroll
            for (int nf = 0; nf < 4; ++nf)
                acc[mf + 4][nf] = __builtin_amdgcn_mfma_f32_16x16x32_bf16(a1[mf], bk0[nf], acc[mf + 4][nf], 0, 0, 0);
        __builtin_amdgcn_s_setprio(0);
        __builtin_amdgcn_s_barrier();

        // ---------- P2: read af[0-3]k1 + bf[0-3]k1 ; stage A1,A3(t+1) ; MFMA mf0-3 k1 ----------
        bf16x8 a2[4], bk1[4];
#pragma unroll
        for (int i = 0; i < 4; ++i)
            a2[i] = *(const bf16x8*)&As[(((wm << 7) + (i << 4) + lr) << 6) + ((32 + (hi << 3)) ^ swzr)];
#pragma unroll
        for (int i = 0; i < 4; ++i)
            bk1[i] = *(const bf16x8*)&Bs[(((wn << 6) + (i << 4) + lr) << 6) + ((32 + (hi << 3)) ^ swzr)];
        if (sN) { stageA(t + 1, pn, 1); stageA(t + 1, pn, 3); }
        __builtin_amdgcn_sched_barrier(0);
        __builtin_amdgcn_s_barrier();
        asm volatile("s_waitcnt lgkmcnt(0)" ::: "memory");
        __builtin_amdgcn_sched_barrier(0);
        __builtin_amdgcn_s_setprio(1);
#pragma unroll
        for (int mf = 0; mf < 4; ++mf)
#pragma unroll
            for (int nf = 0; nf < 4; ++nf)
                acc[mf][nf] = __builtin_amdgcn_mfma_f32_16x16x32_bf16(a2[mf], bk1[nf], acc[mf][nf], 0, 0, 0);
        __builtin_amdgcn_s_setprio(0);
        __builtin_amdgcn_s_barrier();

        // ---------- P3: read af[4-7]k1 ; stage A0,A2(t+2) ; vmcnt ; MFMA mf4-7 k1 ----------
        bf16x8 a3[4];
#pragma unroll
        for (int i = 0; i < 4; ++i)
            a3[i] = *(const bf16x8*)&As[(((wm << 7) + ((i + 4) << 4) + lr) << 6) + ((32 + (hi << 3)) ^ swzr)];
        if (s2) { stageA(t + 2, p, 0); stageA(t + 2, p, 2); }
        if (t <= 69)      asm volatile("s_waitcnt vmcnt(2)" ::: "memory");  // tile t+1 landed
        else if (t == 70) asm volatile("s_waitcnt vmcnt(0)" ::: "memory");  // tail drain
        __builtin_amdgcn_sched_barrier(0);
        __builtin_amdgcn_s_barrier();
        asm volatile("s_waitcnt lgkmcnt(0)" ::: "memory");
        __builtin_amdgcn_sched_barrier(0);
        __builtin_amdgcn_s_setprio(1);
#pragma unroll
        for (int mf = 0; mf < 4; ++mf)
#pragma unroll
            for (int nf = 0; nf < 4; ++nf)
                acc[mf + 4][nf] = __builtin_amdgcn_mfma_f32_16x16x32_bf16(a3[mf], bk1[nf], acc[mf + 4][nf], 0, 0, 0);
        __builtin_amdgcn_s_setprio(0);
        __builtin_amdgcn_s_barrier();
    }

    // fused epilogue: out = leaky(m*y + nw*noise + bias) * sqrt(2), NCHW
    float nw = ldin(nwp, 0, isbf);
    unsigned short* out16 = (unsigned short*)out;
    float* outf = (float*)out;
#pragma unroll
    for (int mf = 0; mf < 8; ++mf) {
        int cobase = co0 + (wm << 7) + (mf << 4) + (hi << 2);
        f32x4 mv = *(const f32x4*)&mmod[b * COUT_ + cobase];
        float bb[4];
#pragma unroll
        for (int r = 0; r < 4; ++r) bb[r] = ldin(bias, cobase + r, isbf);
#pragma unroll
        for (int nf = 0; nf < 4; ++nf) {
            int pix = pl0 + (wn << 6) + (nf << 4) + lr;
            float nv = nw * ldin(noise, b * NPIX + pix, isbf);
#pragma unroll
            for (int r = 0; r < 4; ++r) {
                float v = acc[mf][nf][r] * mv[r] + nv + bb[r];
                v = (v < 0.f ? v * 0.2f : v) * 1.41421356237f;
                size_t oidx = ((size_t)(b * COUT_ + cobase + r)) * NPIX + pix;
                if (isbf) out16[oidx] = f2bf(v);
                else      outf[oidx]  = v;
            }
        }
    }
}

extern "C" void kernel_launch(void* const* d_in, const int* in_sizes, int n_in,
                              void* d_out, int out_size, void* d_ws, size_t ws_size,
                              hipStream_t stream) {
    const void* x      = d_in[0];
    const void* style  = d_in[1];
    const void* noise  = d_in[2];
    const void* kin    = d_in[3];
    const void* sscale = d_in[4];
    const void* bias   = d_in[5];
    const void* nwp    = d_in[6];

    char* ws = (char*)d_ws;
    int* flag = (int*)ws;
    const size_t xtp_off  = 256;
    const size_t xtp_bytes = (size_t)B_ * PADW * PADW * CIN_ * 2;
    const size_t wt_bytes  = (size_t)COUT_ * KTOT * 2;
    unsigned short* xtp = (unsigned short*)(ws + xtp_off);
    unsigned short* wtr = (unsigned short*)(ws + xtp_off + xtp_bytes);
    float* mmod         = (float*)(ws + xtp_off + xtp_bytes + wt_bytes);

    detect_dtype<<<1, 256, 0, stream>>>((const unsigned int*)style, flag);
    halo_zero<<<dim3(260, 8), 256, 0, stream>>>(xtp);
    wt_transpose<<<dim3(8, 72), 256, 0, stream>>>(kin, wtr, flag);
    xpose<<<dim3(8, 64, 8), 256, 0, stream>>>(x, xtp, flag);
    mod_kernel<<<512, 256, 0, stream>>>(style, sscale, wtr, mmod, flag);
    conv_gemm<<<256, 512, 0, stream>>>(wtr, xtp, mmod, noise, bias, nwp, d_out, flag);
}

// Round 5
// 189.081 us; speedup vs baseline: 1.4682x; 1.0283x over previous
//
#include <hip/hip_runtime.h>

#define B_     8
#define CIN_   512
#define COUT_  512
#define HW_    64
#define SDIM_  512
#define NPIX   4096      // pixels per image
#define KTOT   4608      // 9*512
#define PADW   66

typedef __attribute__((ext_vector_type(4))) float f32x4;
typedef __attribute__((ext_vector_type(8))) short bf16x8;
typedef __attribute__((ext_vector_type(8))) unsigned short u16x8;

__device__ __forceinline__ float bf2f(unsigned short b) {
    unsigned int u = ((unsigned int)b) << 16;
    return __builtin_bit_cast(float, u);
}
__device__ __forceinline__ unsigned short f2bf(float f) {
    unsigned int u = __builtin_bit_cast(unsigned int, f);
    return (unsigned short)((u + 0x7fffu + ((u >> 16) & 1u)) >> 16);
}
__device__ __forceinline__ float ldin(const void* p, size_t i, int isbf) {
    return isbf ? bf2f(((const unsigned short*)p)[i]) : ((const float*)p)[i];
}

#define GLD16(g, l) __builtin_amdgcn_global_load_lds( \
    (__attribute__((address_space(1))) void*)(g),     \
    (__attribute__((address_space(3))) void*)(l), 16, 0, 0)

// ---------------- dtype detection (unchanged, verified) ----------------
__global__ void detect_dtype(const unsigned int* __restrict__ style_u32,
                             int* __restrict__ flag) {
    int t = threadIdx.x;
    unsigned int w = style_u32[t * 4];
    int e = (w >> 7) & 0xFF;
    int isbf = (e >= 110 && e <= 140) ? 1 : 0;
    __shared__ int cnt;
    if (t == 0) cnt = 0;
    __syncthreads();
    atomicAdd(&cnt, isbf);
    __syncthreads();
    if (t == 0) *flag = (cnt >= 128) ? 1 : 0;
}

// ---------------- zero only the halo ring of xtp ----------------
__global__ void halo_zero(unsigned short* __restrict__ xtp) {
    int idx = blockIdx.x;        // 0..259
    int b = blockIdx.y;
    int y, x;
    if (idx < 66)       { y = 0;  x = idx; }
    else if (idx < 132) { y = 65; x = idx - 66; }
    else if (idx < 196) { x = 0;  y = idx - 131; }
    else                { x = 65; y = idx - 195; }
    unsigned int* dst = (unsigned int*)(xtp + (((size_t)b * PADW + y) * PADW + x) * CIN_);
    dst[threadIdx.x] = 0;
}

// ---------------- kernel (k,co) -> Wt (co,k) transpose (unchanged) ----------------
__global__ void wt_transpose(const void* __restrict__ kin,
                             unsigned short* __restrict__ wt,
                             const int* __restrict__ flag) {
    __shared__ __align__(16) unsigned short tile[64][72];
    int isbf = *flag;
    int t = threadIdx.x;
    int co0 = blockIdx.x * 64;
    int k0  = blockIdx.y * 64;
    int r = t >> 2, c16 = (t & 3) << 4;
    if (isbf) {
        const unsigned short* src = (const unsigned short*)kin + (size_t)(k0 + r) * COUT_ + co0 + c16;
        *(u16x8*)&tile[r][c16]     = *(const u16x8*)src;
        *(u16x8*)&tile[r][c16 + 8] = *(const u16x8*)(src + 8);
    } else {
        const float* src = (const float*)kin + (size_t)(k0 + r) * COUT_ + co0 + c16;
#pragma unroll
        for (int q = 0; q < 4; ++q) {
            f32x4 v = *(const f32x4*)(src + q * 4);
#pragma unroll
            for (int j = 0; j < 4; ++j) tile[r][c16 + q * 4 + j] = f2bf(v[j]);
        }
    }
    __syncthreads();
    int c = t >> 2, r16 = (t & 3) << 4;
    u16x8 w0, w1;
#pragma unroll
    for (int j = 0; j < 8; ++j) { w0[j] = tile[r16 + j][c]; w1[j] = tile[r16 + 8 + j][c]; }
    unsigned short* dst = wt + (size_t)(co0 + c) * KTOT + k0 + r16;
    *(u16x8*)dst       = w0;
    *(u16x8*)(dst + 8) = w1;
}

// ---------------- x NCHW -> padded bf16 NHWC (unchanged) ----------------
__global__ void xpose(const void* __restrict__ x,
                      unsigned short* __restrict__ xtp,
                      const int* __restrict__ flag) {
    __shared__ __align__(16) unsigned short tile[64][72];
    int isbf = *flag;
    int t = threadIdx.x;
    int cit = blockIdx.x;
    int y   = blockIdx.y;
    int b   = blockIdx.z;
    int ci_l = t >> 2, xo = (t & 3) << 4;
    size_t srcoff = (((size_t)(b * CIN_ + cit * 64 + ci_l)) * HW_ + y) * HW_ + xo;
    if (isbf) {
        const unsigned short* src = (const unsigned short*)x + srcoff;
        *(u16x8*)&tile[ci_l][xo]     = *(const u16x8*)src;
        *(u16x8*)&tile[ci_l][xo + 8] = *(const u16x8*)(src + 8);
    } else {
        const float* src = (const float*)x + srcoff;
#pragma unroll
        for (int q = 0; q < 4; ++q) {
            f32x4 v = *(const f32x4*)(src + q * 4);
#pragma unroll
            for (int j = 0; j < 4; ++j) tile[ci_l][xo + q * 4 + j] = f2bf(v[j]);
        }
    }
    __syncthreads();
    int xl = t >> 2, cio = (t & 3) << 4;
    u16x8 w0, w1;
#pragma unroll
    for (int j = 0; j < 8; ++j) { w0[j] = tile[cio + j][xl]; w1[j] = tile[cio + 8 + j][xl]; }
    unsigned short* dst =
        xtp + (((size_t)b * PADW + (y + 1)) * PADW + (xl + 1)) * CIN_ + cit * 64 + cio;
    *(u16x8*)dst       = w0;
    *(u16x8*)(dst + 8) = w1;
}

// ---------------- mod scale (unchanged) ----------------
__global__ void mod_kernel(const void* __restrict__ style,
                           const void* __restrict__ sscale,
                           const unsigned short* __restrict__ wt,
                           float* __restrict__ mmod,
                           const int* __restrict__ flag) {
    int isbf = *flag;
    int co = blockIdx.x, t = threadIdx.x;
    int lane = t & 63, wid = t >> 6;
    float k2 = 0.f;
    const unsigned short* wr = wt + (size_t)co * KTOT;
    for (int k = t; k < KTOT; k += 256) { float v = bf2f(wr[k]); k2 += v * v; }
    float sb[B_];
#pragma unroll
    for (int b = 0; b < B_; ++b) sb[b] = 0.f;
    for (int sd = t; sd < SDIM_; sd += 256) {
        float ss = ldin(sscale, (size_t)sd * COUT_ + co, isbf);
#pragma unroll
        for (int b = 0; b < B_; ++b) sb[b] += ldin(style, b * SDIM_ + sd, isbf) * ss;
    }
    __shared__ float red[4][9];
    float vals[9];
    vals[0] = k2;
#pragma unroll
    for (int b = 0; b < B_; ++b) vals[1 + b] = sb[b];
#pragma unroll
    for (int q = 0; q < 9; ++q) {
        float v = vals[q];
        for (int off = 32; off; off >>= 1) v += __shfl_down(v, off);
        if (lane == 0) red[wid][q] = v;
    }
    __syncthreads();
    if (t < B_) {
        int b = t;
        float k2t = red[0][0] + red[1][0] + red[2][0] + red[3][0];
        float s   = red[0][1 + b] + red[1][1 + b] + red[2][1 + b] + red[3][1 + b];
        float sp1 = s + 1.f;
        mmod[b * COUT_ + co] = sp1 * rsqrtf(sp1 * sp1 * k2t + 1e-8f);
    }
}

// ---------------- implicit-GEMM conv, 256x256, 8 waves, 4-phase + deep prefetch ----------------
// Staging (tile t steady state; buf p = t&1, pn = p^1):
//   P0: stage A1,A3,B0,B1 (t+1 -> pn)   [pn fully released at (t-1).P3]
//   P1: stage B2,B3       (t+1 -> pn)
//   P3: stage A0,A2       (t+2 -> p)    [p's A0,A2 released at t.P2]
//        MFMA, then vmcnt(2): waits all 8 of t+1 (lead >= 2.5 phases), keeps t+2 in flight.
__global__ __launch_bounds__(512, 2) void conv_gemm(
    const unsigned short* __restrict__ wt,
    const unsigned short* __restrict__ xtp,
    const float* __restrict__ mmod,
    const void* __restrict__ noise,
    const void* __restrict__ bias,
    const void* __restrict__ nwp,
    void* __restrict__ out,
    const int* __restrict__ flag) {
    __shared__ __align__(1024) unsigned short Asm[2][256 * 64];   // 64 KiB
    __shared__ __align__(1024) unsigned short Bsm[2][256 * 64];   // 64 KiB
    int isbf = *flag;
    int tid = threadIdx.x;
    int lane = tid & 63, wid = tid >> 6;
    int lr = lane & 15, hi = lane >> 4;
    int wm = wid >> 2, wn = wid & 3;          // 2 x 4 wave grid

    int bid = blockIdx.x;
    int swz = (bid & 7) * 32 + (bid >> 3);    // XCD-chunked bijective (256 % 8 == 0)
    int gy = swz >> 7;
    int nb = swz & 127;
    int b  = nb >> 4;
    int nt = nb & 15;
    int pl0 = nt << 8;                        // 256 pixels = 4 rows
    int h0  = pl0 >> 6;
    int co0 = gy << 8;

    const unsigned short* xb = xtp + (size_t)b * (PADW * PADW * CIN_);

    f32x4 acc[8][4];
#pragma unroll
    for (int i = 0; i < 8; ++i)
#pragma unroll
        for (int j = 0; j < 4; ++j) acc[i][j] = (f32x4){0.f, 0.f, 0.f, 0.f};

    int rsub = lane >> 3;
    int ce_src = ((lane & 7) ^ rsub) << 3;    // pre-swizzled source column (elements)
    int swzr = (lane & 7) << 3;               // read-side XOR

    auto stageA = [&](int tt, int pp, int q) {
        const unsigned short* srcA =
            wt + (size_t)(co0 + (q << 6) + (wid << 3) + rsub) * KTOT + (tt << 6) + ce_src;
        GLD16(srcA, (char*)&Asm[pp][0] + (q << 13) + (wid << 10));
    };
    auto stageB = [&](int tt, int pp, int q) {
        int khw = tt >> 3;
        int kh = (khw >= 6) ? 2 : ((khw >= 3) ? 1 : 0);
        int kw = khw - kh * 3;
        int ci0 = (tt & 7) << 6;
        int wc = ((wid << 3) + rsub) & 63;
        const unsigned short* srcB =
            xb + ((size_t)(h0 + q + kh) * PADW + (wc + kw)) * CIN_ + ci0 + ce_src;
        GLD16(srcB, (char*)&Bsm[pp][0] + (q << 13) + (wid << 10));
    };

    // prologue: tiles 0 and 1 fully staged
#pragma unroll
    for (int q = 0; q < 4; ++q) { stageA(0, 0, q); stageB(0, 0, q); }
#pragma unroll
    for (int q = 0; q < 4; ++q) { stageA(1, 1, q); stageB(1, 1, q); }
    asm volatile("s_waitcnt vmcnt(8)" ::: "memory");   // tile 0 landed
    __builtin_amdgcn_s_barrier();
    __builtin_amdgcn_sched_barrier(0);

    for (int t = 0; t < 72; ++t) {
        int p = t & 1, pn = p ^ 1;
        const unsigned short* As = &Asm[p][0];
        const unsigned short* Bs = &Bsm[p][0];
        bool sN = (t >= 1 && t <= 70);        // stage tile t+1 (t=0: prestaged)
        bool s2 = (t <= 69);                  // stage tile t+2 A0,A2

        // ---------- P0: read af[0-3]k0 + bf[0-3]k0 ; stage A1,A3,B0,B1(t+1) ; MFMA mf0-3 k0 ----------
        bf16x8 a0[4], bk0[4];
#pragma unroll
        for (int i = 0; i < 4; ++i)
            a0[i] = *(const bf16x8*)&As[(((wm << 7) + (i << 4) + lr) << 6) + ((hi << 3) ^ swzr)];
#pragma unroll
        for (int i = 0; i < 4; ++i)
            bk0[i] = *(const bf16x8*)&Bs[(((wn << 6) + (i << 4) + lr) << 6) + ((hi << 3) ^ swzr)];
        if (sN) { stageA(t + 1, pn, 1); stageA(t + 1, pn, 3); stageB(t + 1, pn, 0); stageB(t + 1, pn, 1); }
        __builtin_amdgcn_sched_barrier(0);
        __builtin_amdgcn_s_barrier();
        asm volatile("s_waitcnt lgkmcnt(0)" ::: "memory");
        __builtin_amdgcn_sched_barrier(0);
        __builtin_amdgcn_s_setprio(1);
#pragma unroll
        for (int mf = 0; mf < 4; ++mf)
#pragma unroll
            for (int nf = 0; nf < 4; ++nf)
                acc[mf][nf] = __builtin_amdgcn_mfma_f32_16x16x32_bf16(a0[mf], bk0[nf], acc[mf][nf], 0, 0, 0);
        __builtin_amdgcn_s_setprio(0);
        __builtin_amdgcn_s_barrier();

        // ---------- P1: read af[4-7]k0 ; stage B2,B3(t+1) ; MFMA mf4-7 k0 ----------
        bf16x8 a1[4];
#pragma unroll
        for (int i = 0; i < 4; ++i)
            a1[i] = *(const bf16x8*)&As[(((wm << 7) + ((i + 4) << 4) + lr) << 6) + ((hi << 3) ^ swzr)];
        if (sN) { stageB(t + 1, pn, 2); stageB(t + 1, pn, 3); }
        __builtin_amdgcn_sched_barrier(0);
        __builtin_amdgcn_s_barrier();
        asm volatile("s_waitcnt lgkmcnt(0)" ::: "memory");
        __builtin_amdgcn_sched_barrier(0);
        __builtin_amdgcn_s_setprio(1);
#pragma unroll
        for (int mf = 0; mf < 4; ++mf)
#pragma unroll
            for (int nf = 0; nf < 4; ++nf)
                acc[mf + 4][nf] = __builtin_amdgcn_mfma_f32_16x16x32_bf16(a1[mf], bk0[nf], acc[mf + 4][nf], 0, 0, 0);
        __builtin_amdgcn_s_setprio(0);
        __builtin_amdgcn_s_barrier();

        // ---------- P2: read af[0-3]k1 + bf[0-3]k1 ; MFMA mf0-3 k1 ----------
        bf16x8 a2[4], bk1[4];
#pragma unroll
        for (int i = 0; i < 4; ++i)
            a2[i] = *(const bf16x8*)&As[(((wm << 7) + (i << 4) + lr) << 6) + ((32 + (hi << 3)) ^ swzr)];
#pragma unroll
        for (int i = 0; i < 4; ++i)
            bk1[i] = *(const bf16x8*)&Bs[(((wn << 6) + (i << 4) + lr) << 6) + ((32 + (hi << 3)) ^ swzr)];
        __builtin_amdgcn_sched_barrier(0);
        __builtin_amdgcn_s_barrier();
        asm volatile("s_waitcnt lgkmcnt(0)" ::: "memory");
        __builtin_amdgcn_sched_barrier(0);
        __builtin_amdgcn_s_setprio(1);
#pragma unroll
        for (int mf = 0; mf < 4; ++mf)
#pragma unroll
            for (int nf = 0; nf < 4; ++nf)
                acc[mf][nf] = __builtin_amdgcn_mfma_f32_16x16x32_bf16(a2[mf], bk1[nf], acc[mf][nf], 0, 0, 0);
        __builtin_amdgcn_s_setprio(0);
        __builtin_amdgcn_s_barrier();

        // ---------- P3: read af[4-7]k1 ; stage A0,A2(t+2) ; MFMA mf4-7 k1 ; vmcnt ----------
        bf16x8 a3[4];
#pragma unroll
        for (int i = 0; i < 4; ++i)
            a3[i] = *(const bf16x8*)&As[(((wm << 7) + ((i + 4) << 4) + lr) << 6) + ((32 + (hi << 3)) ^ swzr)];
        if (s2) { stageA(t + 2, p, 0); stageA(t + 2, p, 2); }
        __builtin_amdgcn_sched_barrier(0);
        __builtin_amdgcn_s_barrier();
        asm volatile("s_waitcnt lgkmcnt(0)" ::: "memory");
        __builtin_amdgcn_sched_barrier(0);
        __builtin_amdgcn_s_setprio(1);
#pragma unroll
        for (int mf = 0; mf < 4; ++mf)
#pragma unroll
            for (int nf = 0; nf < 4; ++nf)
                acc[mf + 4][nf] = __builtin_amdgcn_mfma_f32_16x16x32_bf16(a3[mf], bk1[nf], acc[mf + 4][nf], 0, 0, 0);
        __builtin_amdgcn_s_setprio(0);
        if (t <= 69)      asm volatile("s_waitcnt vmcnt(2)" ::: "memory");  // t+1 landed, t+2 in flight
        else if (t == 70) asm volatile("s_waitcnt vmcnt(0)" ::: "memory");  // tail drain
        __builtin_amdgcn_sched_barrier(0);
        __builtin_amdgcn_s_barrier();
    }

    // fused epilogue: out = leaky(m*y + nw*noise + bias) * sqrt(2), NCHW
    float nw = ldin(nwp, 0, isbf);
    unsigned short* out16 = (unsigned short*)out;
    float* outf = (float*)out;
#pragma unroll
    for (int mf = 0; mf < 8; ++mf) {
        int cobase = co0 + (wm << 7) + (mf << 4) + (hi << 2);
        f32x4 mv = *(const f32x4*)&mmod[b * COUT_ + cobase];
        float bb[4];
#pragma unroll
        for (int r = 0; r < 4; ++r) bb[r] = ldin(bias, cobase + r, isbf);
#pragma unroll
        for (int nf = 0; nf < 4; ++nf) {
            int pix = pl0 + (wn << 6) + (nf << 4) + lr;
            float nv = nw * ldin(noise, b * NPIX + pix, isbf);
#pragma unroll
            for (int r = 0; r < 4; ++r) {
                float v = acc[mf][nf][r] * mv[r] + nv + bb[r];
                v = (v < 0.f ? v * 0.2f : v) * 1.41421356237f;
                size_t oidx = ((size_t)(b * COUT_ + cobase + r)) * NPIX + pix;
                if (isbf) out16[oidx] = f2bf(v);
                else      outf[oidx]  = v;
            }
        }
    }
}

extern "C" void kernel_launch(void* const* d_in, const int* in_sizes, int n_in,
                              void* d_out, int out_size, void* d_ws, size_t ws_size,
                              hipStream_t stream) {
    const void* x      = d_in[0];
    const void* style  = d_in[1];
    const void* noise  = d_in[2];
    const void* kin    = d_in[3];
    const void* sscale = d_in[4];
    const void* bias   = d_in[5];
    const void* nwp    = d_in[6];

    char* ws = (char*)d_ws;
    int* flag = (int*)ws;
    const size_t xtp_off  = 256;
    const size_t xtp_bytes = (size_t)B_ * PADW * PADW * CIN_ * 2;
    const size_t wt_bytes  = (size_t)COUT_ * KTOT * 2;
    unsigned short* xtp = (unsigned short*)(ws + xtp_off);
    unsigned short* wtr = (unsigned short*)(ws + xtp_off + xtp_bytes);
    float* mmod         = (float*)(ws + xtp_off + xtp_bytes + wt_bytes);

    detect_dtype<<<1, 256, 0, stream>>>((const unsigned int*)style, flag);
    halo_zero<<<dim3(260, 8), 256, 0, stream>>>(xtp);
    wt_transpose<<<dim3(8, 72), 256, 0, stream>>>(kin, wtr, flag);
    xpose<<<dim3(8, 64, 8), 256, 0, stream>>>(x, xtp, flag);
    mod_kernel<<<512, 256, 0, stream>>>(style, sscale, wtr, mmod, flag);
    conv_gemm<<<256, 512, 0, stream>>>(wtr, xtp, mmod, noise, bias, nwp, d_out, flag);
}